// Round 4
// baseline (104.956 us; speedup 1.0000x reference)
//
#include <hip/hip_runtime.h>
#include <math.h>

// CuboidAlignment, R4: R3 with compile fix — nontemporal builtins need clang
// ext_vector_type, not HIP_vector_type<float,4>.
// Kernel is ~13us (HBM floor for 84MB traffic); dur_us is dominated by
// harness re-poison fills (2x 256MiB @ ~6.2TB/s == ~86us, seen in rocprof).

#define FLOOR_Z_VAL (-1.6)

typedef float f32x4 __attribute__((ext_vector_type(4)));

__device__ __forceinline__ void sincospi_d(double x, double* sp, double* cp) {
    double n = rint(2.0 * x);
    double r = fma(n, -0.5, x);      // r in [-0.25, 0.25]
    int q = ((int)n) & 3;
    double t = r * r;
    double ps = -2.1915353447830215e-05;
    ps = fma(ps, t,  4.6630280576761010e-04);
    ps = fma(ps, t, -7.3704309457143504e-03);
    ps = fma(ps, t,  8.2145886611128228e-02);
    ps = fma(ps, t, -5.9926452932079207e-01);
    ps = fma(ps, t,  2.5501640398773455e+00);
    ps = fma(ps, t, -5.1677127800499700e+00);
    ps = fma(ps, t,  3.1415926535897931e+00);
    double s = r * ps;
    double pc =  4.3030695870329470e-06;
    pc = fma(pc, t, -1.0463810492484570e-04);
    pc = fma(pc, t,  1.9295743094039231e-03);
    pc = fma(pc, t, -2.5806891390014061e-02);
    pc = fma(pc, t,  2.3533063035889320e-01);
    pc = fma(pc, t, -1.3352627688545894e+00);
    pc = fma(pc, t,  4.0587121264167682e+00);
    pc = fma(pc, t, -4.9348022005446793e+00);
    double c = fma(pc, t, 1.0);
    double bs = (q & 1) ? c : s;
    double bc = (q & 1) ? s : c;
    *sp = (q & 2) ? -bs : bs;
    *cp = ((q + 1) & 2) ? -bc : bc;
}

// tan(pi*x) for x in (0.0, 0.5): sinpi(x)/cospi(x). 9 f32 FMAs + div.
__device__ __forceinline__ float tanpi_f(float x) {
    float n = rintf(2.0f * x);       // 0 or 1
    float r = fmaf(n, -0.5f, x);     // [-0.25, 0.25]
    float t = r * r;
    float ps = fmaf(-0.59926453f, t, 2.55016404f);
    ps = fmaf(ps, t, -5.16771278f);
    ps = fmaf(ps, t,  3.14159265f);
    float s = r * ps;
    float pc = fmaf(0.23533063f, t, -1.33526277f);
    pc = fmaf(pc, t,  4.05871213f);
    pc = fmaf(pc, t, -4.93480220f);
    float c = fmaf(pc, t, 1.0f);
    float sp = (n != 0.0f) ? c : s;
    float cp = (n != 0.0f) ? -s : c;
    return sp / cp;
}

__global__ __launch_bounds__(256) void cuboid_kernel(
    const float* __restrict__ top_c,   // (B,4,2)
    const float* __restrict__ bot_c,   // (B,4,2)
    const float* __restrict__ cub,     // (1,4,2)
    float* __restrict__ out,           // top (B,4,3) then bottom (B,4,3)
    int B)
{
    int b = blockIdx.x * blockDim.x + threadIdx.x;
    if (b >= B) return;

    const f32x4* bp = (const f32x4*)(bot_c + (size_t)b * 8);
    const f32x4* tp = (const f32x4*)(top_c + (size_t)b * 8);
    f32x4 bc0 = __builtin_nontemporal_load(bp);
    f32x4 bc1 = __builtin_nontemporal_load(bp + 1);
    f32x4 tc0 = __builtin_nontemporal_load(tp);
    f32x4 tc1 = __builtin_nontemporal_load(tp + 1);

    double bu[4] = {(double)bc0.x, (double)bc0.z, (double)bc1.x, (double)bc1.z};
    double bv[4] = {(double)bc0.y, (double)bc0.w, (double)bc1.y, (double)bc1.w};
    float  tv[4] = {tc0.y, tc0.w, tc1.y, tc1.w};

    // floor_xy in f64 (ordering-critical)
    double X[4], Y[4];
#pragma unroll
    for (int i = 0; i < 4; ++i) {
        double su, cu, sv, cv;
        sincospi_d(bu[i], &su, &cu);
        sincospi_d(-0.5 * bv[i], &sv, &cv);
        double c = (FLOOR_Z_VAL * cv) / sv;   // floor_z / tan(v)
        X[i] = c * su;
        Y[i] = -c * cu;
    }
    double cx = 0.25 * (X[0] + X[1] + X[2] + X[3]);
    double cy = 0.25 * (Y[0] + Y[1] + Y[2] + Y[3]);

    // argsort of atan2(X-cx, Y-cy+1e-12) without atan2
    double hx[4], hy[4];
    int h[4];
#pragma unroll
    for (int i = 0; i < 4; ++i) {
        hx[i] = (Y[i] - cy) + 1e-12;
        hy[i] = X[i] - cx;
        h[i] = (hy[i] < 0.0) ? 0 : 1;
    }
    int rank[4];
#pragma unroll
    for (int k = 0; k < 4; ++k) {
        int r = 0;
#pragma unroll
        for (int m = 0; m < 4; ++m) {
            if (m == k) continue;
            bool before;
            if (h[m] != h[k]) {
                before = h[m] < h[k];
            } else {
                double cr = hx[m] * hy[k] - hy[m] * hx[k];
                before = (cr > 0.0) || (cr == 0.0 && m < k);
            }
            r += before ? 1 : 0;
        }
        rank[k] = r;
    }

    // float stage
    float Xf[4], Yf[4];
#pragma unroll
    for (int i = 0; i < 4; ++i) { Xf[i] = (float)X[i]; Yf[i] = (float)Y[i]; }
    float cxf = (float)cx, cyf = (float)cy;

    float d01x = Xf[0]-Xf[1], d01y = Yf[0]-Yf[1];
    float d12x = Xf[1]-Xf[2], d12y = Yf[1]-Yf[2];
    float d23x = Xf[2]-Xf[3], d23y = Yf[2]-Yf[3];
    float d30x = Xf[3]-Xf[0], d30y = Yf[3]-Yf[0];
    float ax1 = sqrtf(d01x*d01x + d01y*d01y);
    float ay1 = sqrtf(d12x*d12x + d12y*d12y);
    float ax2 = sqrtf(d23x*d23x + d23y*d23y);
    float ay2 = sqrtf(d30x*d30x + d30y*d30y);
    float s0 = 0.25f * (ay1 + ay2);
    float s1 = 0.25f * (ax1 + ax2);

    float ceil_z = 0.f;
#pragma unroll
    for (int i = 0; i < 4; ++i) {
        float cn = sqrtf(Xf[i]*Xf[i] + Yf[i]*Yf[i]);
        ceil_z += cn * tanpi_f(-0.5f * tv[i]);   // tan(tv * -pi/2)
    }
    ceil_z *= 0.25f;

    float Cux[4], Cuy[4];
#pragma unroll
    for (int k = 0; k < 4; ++k) { Cux[k] = cub[2*k]; Cuy[k] = cub[2*k+1]; }

    float rx[4], ry[4];
#pragma unroll
    for (int k = 0; k < 4; ++k) {
        rx[k] = Cux[k] * s0 + cxf;
        ry[k] = Cuy[k] * s1 + cyf;
    }
    float c1x = 0.25f*(rx[0]+rx[1]+rx[2]+rx[3]);
    float c1y = 0.25f*(ry[0]+ry[1]+ry[2]+ry[3]);

    float var = 0.f, K00 = 0.f, K01 = 0.f, K10 = 0.f, K11 = 0.f;
#pragma unroll
    for (int k = 0; k < 4; ++k) {
        float p1x = rx[k]-c1x, p1y = ry[k]-c1y;
        float p2x = Xf[k]-c1x, p2y = Yf[k]-c1y;
        var += p1x*p1x + p1y*p1y;
        K00 += p1x*p2x; K01 += p1x*p2y;
        K10 += p1y*p2x; K11 += p1y*p2y;
    }
    float A  = K00 + K11;
    float Bb = K01 - K10;
    float ivar = 1.f / var;
    float m00 = A * ivar, m01 = -Bb * ivar;
    float m10 = Bb * ivar, m11 = A * ivar;

    float px[4], py[4];
#pragma unroll
    for (int k = 0; k < 4; ++k) {
        float dx = rx[k] - c1x, dy = ry[k] - c1y;
        px[k] = m00*dx + m01*dy + c1x;
        py[k] = m10*dx + m11*dy + c1y;
    }

    float ox[4], oy[4];
#pragma unroll
    for (int j = 0; j < 4; ++j) {
        float vx = 0.f, vy = 0.f;
#pragma unroll
        for (int k = 0; k < 4; ++k) {
            bool sel = (rank[k] == j);
            vx = sel ? px[k] : vx;
            vy = sel ? py[k] : vy;
        }
        ox[j] = vx; oy[j] = vy;
    }

    float fz = (float)FLOOR_Z_VAL;
    f32x4* ot4 = (f32x4*)(out + (size_t)b * 12);
    __builtin_nontemporal_store((f32x4){ox[0], oy[0], ceil_z, ox[1]}, ot4);
    __builtin_nontemporal_store((f32x4){oy[1], ceil_z, ox[2], oy[2]}, ot4 + 1);
    __builtin_nontemporal_store((f32x4){ceil_z, ox[3], oy[3], ceil_z}, ot4 + 2);
    f32x4* ob4 = (f32x4*)(out + (size_t)B * 12 + (size_t)b * 12);
    __builtin_nontemporal_store((f32x4){ox[0], oy[0], fz, ox[1]}, ob4);
    __builtin_nontemporal_store((f32x4){oy[1], fz, ox[2], oy[2]}, ob4 + 1);
    __builtin_nontemporal_store((f32x4){fz, ox[3], oy[3], fz}, ob4 + 2);
}

extern "C" void kernel_launch(void* const* d_in, const int* in_sizes, int n_in,
                              void* d_out, int out_size, void* d_ws, size_t ws_size,
                              hipStream_t stream) {
    const float* top_c = (const float*)d_in[0];
    const float* bot_c = (const float*)d_in[1];
    const float* cub   = (const float*)d_in[2];
    float* out = (float*)d_out;
    int B = in_sizes[0] / 8;
    int block = 256;
    int grid = (B + block - 1) / block;
    hipLaunchKernelGGL(cuboid_kernel, dim3(grid), dim3(block), 0, stream,
                       top_c, bot_c, cub, out, B);
}

// Round 5
// 97.805 us; speedup vs baseline: 1.0731x; 1.0731x over previous
//
#include <hip/hip_runtime.h>
#include <math.h>

// CuboidAlignment, R5: A/B revert of R4's nontemporal accesses (regressed
// 97.7 -> 105.0 us vs predicted -3; isolating). Keeps R4's tanpi_f (9-FMA
// poly replacing libm tanf). Otherwise identical to R2 (passed, 97.7us).
// Kernel-side time ~13-16us vs 13.3us HBM floor (84MB traffic @ 6.3TB/s);
// measured dur_us additionally contains ~86us of harness re-poison fills
// (2x 256MiB @ ~6.2TB/s, visible as fillBufferAligned in rocprof top-5).

#define FLOOR_Z_VAL (-1.6)

__device__ __forceinline__ void sincospi_d(double x, double* sp, double* cp) {
    double n = rint(2.0 * x);
    double r = fma(n, -0.5, x);      // r in [-0.25, 0.25]
    int q = ((int)n) & 3;
    double t = r * r;
    double ps = -2.1915353447830215e-05;
    ps = fma(ps, t,  4.6630280576761010e-04);
    ps = fma(ps, t, -7.3704309457143504e-03);
    ps = fma(ps, t,  8.2145886611128228e-02);
    ps = fma(ps, t, -5.9926452932079207e-01);
    ps = fma(ps, t,  2.5501640398773455e+00);
    ps = fma(ps, t, -5.1677127800499700e+00);
    ps = fma(ps, t,  3.1415926535897931e+00);
    double s = r * ps;
    double pc =  4.3030695870329470e-06;
    pc = fma(pc, t, -1.0463810492484570e-04);
    pc = fma(pc, t,  1.9295743094039231e-03);
    pc = fma(pc, t, -2.5806891390014061e-02);
    pc = fma(pc, t,  2.3533063035889320e-01);
    pc = fma(pc, t, -1.3352627688545894e+00);
    pc = fma(pc, t,  4.0587121264167682e+00);
    pc = fma(pc, t, -4.9348022005446793e+00);
    double c = fma(pc, t, 1.0);
    double bs = (q & 1) ? c : s;
    double bc = (q & 1) ? s : c;
    *sp = (q & 2) ? -bs : bs;
    *cp = ((q + 1) & 2) ? -bc : bc;
}

// tan(pi*x) for x in (0.0, 0.5): sinpi(x)/cospi(x). 9 f32 FMAs + div.
__device__ __forceinline__ float tanpi_f(float x) {
    float n = rintf(2.0f * x);       // 0 or 1
    float r = fmaf(n, -0.5f, x);     // [-0.25, 0.25]
    float t = r * r;
    float ps = fmaf(-0.59926453f, t, 2.55016404f);
    ps = fmaf(ps, t, -5.16771278f);
    ps = fmaf(ps, t,  3.14159265f);
    float s = r * ps;
    float pc = fmaf(0.23533063f, t, -1.33526277f);
    pc = fmaf(pc, t,  4.05871213f);
    pc = fmaf(pc, t, -4.93480220f);
    float c = fmaf(pc, t, 1.0f);
    float sp = (n != 0.0f) ? c : s;
    float cp = (n != 0.0f) ? -s : c;
    return sp / cp;
}

__global__ __launch_bounds__(256) void cuboid_kernel(
    const float* __restrict__ top_c,   // (B,4,2)
    const float* __restrict__ bot_c,   // (B,4,2)
    const float* __restrict__ cub,     // (1,4,2)
    float* __restrict__ out,           // top (B,4,3) then bottom (B,4,3)
    int B)
{
    int b = blockIdx.x * blockDim.x + threadIdx.x;
    if (b >= B) return;

    float4 bc0 = *(const float4*)(bot_c + (size_t)b * 8);
    float4 bc1 = *(const float4*)(bot_c + (size_t)b * 8 + 4);
    float4 tc0 = *(const float4*)(top_c + (size_t)b * 8);
    float4 tc1 = *(const float4*)(top_c + (size_t)b * 8 + 4);

    double bu[4] = {(double)bc0.x, (double)bc0.z, (double)bc1.x, (double)bc1.z};
    double bv[4] = {(double)bc0.y, (double)bc0.w, (double)bc1.y, (double)bc1.w};
    float  tv[4] = {tc0.y, tc0.w, tc1.y, tc1.w};

    // floor_xy in f64 (ordering-critical)
    double X[4], Y[4];
#pragma unroll
    for (int i = 0; i < 4; ++i) {
        double su, cu, sv, cv;
        sincospi_d(bu[i], &su, &cu);
        sincospi_d(-0.5 * bv[i], &sv, &cv);
        double c = (FLOOR_Z_VAL * cv) / sv;   // floor_z / tan(v)
        X[i] = c * su;
        Y[i] = -c * cu;
    }
    double cx = 0.25 * (X[0] + X[1] + X[2] + X[3]);
    double cy = 0.25 * (Y[0] + Y[1] + Y[2] + Y[3]);

    // argsort of atan2(X-cx, Y-cy+1e-12) without atan2
    double hx[4], hy[4];
    int h[4];
#pragma unroll
    for (int i = 0; i < 4; ++i) {
        hx[i] = (Y[i] - cy) + 1e-12;
        hy[i] = X[i] - cx;
        h[i] = (hy[i] < 0.0) ? 0 : 1;
    }
    int rank[4];
#pragma unroll
    for (int k = 0; k < 4; ++k) {
        int r = 0;
#pragma unroll
        for (int m = 0; m < 4; ++m) {
            if (m == k) continue;
            bool before;
            if (h[m] != h[k]) {
                before = h[m] < h[k];
            } else {
                double cr = hx[m] * hy[k] - hy[m] * hx[k];
                before = (cr > 0.0) || (cr == 0.0 && m < k);
            }
            r += before ? 1 : 0;
        }
        rank[k] = r;
    }

    // float stage
    float Xf[4], Yf[4];
#pragma unroll
    for (int i = 0; i < 4; ++i) { Xf[i] = (float)X[i]; Yf[i] = (float)Y[i]; }
    float cxf = (float)cx, cyf = (float)cy;

    float d01x = Xf[0]-Xf[1], d01y = Yf[0]-Yf[1];
    float d12x = Xf[1]-Xf[2], d12y = Yf[1]-Yf[2];
    float d23x = Xf[2]-Xf[3], d23y = Yf[2]-Yf[3];
    float d30x = Xf[3]-Xf[0], d30y = Yf[3]-Yf[0];
    float ax1 = sqrtf(d01x*d01x + d01y*d01y);
    float ay1 = sqrtf(d12x*d12x + d12y*d12y);
    float ax2 = sqrtf(d23x*d23x + d23y*d23y);
    float ay2 = sqrtf(d30x*d30x + d30y*d30y);
    float s0 = 0.25f * (ay1 + ay2);
    float s1 = 0.25f * (ax1 + ax2);

    float ceil_z = 0.f;
#pragma unroll
    for (int i = 0; i < 4; ++i) {
        float cn = sqrtf(Xf[i]*Xf[i] + Yf[i]*Yf[i]);
        ceil_z += cn * tanpi_f(-0.5f * tv[i]);   // tan(tv * -pi/2)
    }
    ceil_z *= 0.25f;

    float Cux[4], Cuy[4];
#pragma unroll
    for (int k = 0; k < 4; ++k) { Cux[k] = cub[2*k]; Cuy[k] = cub[2*k+1]; }

    float rx[4], ry[4];
#pragma unroll
    for (int k = 0; k < 4; ++k) {
        rx[k] = Cux[k] * s0 + cxf;
        ry[k] = Cuy[k] * s1 + cyf;
    }
    float c1x = 0.25f*(rx[0]+rx[1]+rx[2]+rx[3]);
    float c1y = 0.25f*(ry[0]+ry[1]+ry[2]+ry[3]);

    float var = 0.f, K00 = 0.f, K01 = 0.f, K10 = 0.f, K11 = 0.f;
#pragma unroll
    for (int k = 0; k < 4; ++k) {
        float p1x = rx[k]-c1x, p1y = ry[k]-c1y;
        float p2x = Xf[k]-c1x, p2y = Yf[k]-c1y;
        var += p1x*p1x + p1y*p1y;
        K00 += p1x*p2x; K01 += p1x*p2y;
        K10 += p1y*p2x; K11 += p1y*p2y;
    }
    float A  = K00 + K11;
    float Bb = K01 - K10;
    float ivar = 1.f / var;
    float m00 = A * ivar, m01 = -Bb * ivar;
    float m10 = Bb * ivar, m11 = A * ivar;

    float px[4], py[4];
#pragma unroll
    for (int k = 0; k < 4; ++k) {
        float dx = rx[k] - c1x, dy = ry[k] - c1y;
        px[k] = m00*dx + m01*dy + c1x;
        py[k] = m10*dx + m11*dy + c1y;
    }

    float ox[4], oy[4];
#pragma unroll
    for (int j = 0; j < 4; ++j) {
        float vx = 0.f, vy = 0.f;
#pragma unroll
        for (int k = 0; k < 4; ++k) {
            bool sel = (rank[k] == j);
            vx = sel ? px[k] : vx;
            vy = sel ? py[k] : vy;
        }
        ox[j] = vx; oy[j] = vy;
    }

    float fz = (float)FLOOR_Z_VAL;
    float4* ot4 = (float4*)(out + (size_t)b * 12);
    ot4[0] = make_float4(ox[0], oy[0], ceil_z, ox[1]);
    ot4[1] = make_float4(oy[1], ceil_z, ox[2], oy[2]);
    ot4[2] = make_float4(ceil_z, ox[3], oy[3], ceil_z);
    float4* ob4 = (float4*)(out + (size_t)B * 12 + (size_t)b * 12);
    ob4[0] = make_float4(ox[0], oy[0], fz, ox[1]);
    ob4[1] = make_float4(oy[1], fz, ox[2], oy[2]);
    ob4[2] = make_float4(fz, ox[3], oy[3], fz);
}

extern "C" void kernel_launch(void* const* d_in, const int* in_sizes, int n_in,
                              void* d_out, int out_size, void* d_ws, size_t ws_size,
                              hipStream_t stream) {
    const float* top_c = (const float*)d_in[0];
    const float* bot_c = (const float*)d_in[1];
    const float* cub   = (const float*)d_in[2];
    float* out = (float*)d_out;
    int B = in_sizes[0] / 8;
    int block = 256;
    int grid = (B + block - 1) / block;
    hipLaunchKernelGGL(cuboid_kernel, dim3(grid), dim3(block), 0, stream,
                       top_c, bot_c, cub, out, B);
}